// Round 1
// baseline (908.156 us; speedup 1.0000x reference)
//
#include <hip/hip_runtime.h>
#include <hip/hip_bf16.h>

#define Nn 100000
#define Ee 1600000
#define Ff 128
#define Hh 128
#define Cc 10
#define Gg 512

typedef short bf16x8 __attribute__((ext_vector_type(8)));
typedef float f32x4 __attribute__((ext_vector_type(4)));

__device__ __forceinline__ unsigned short f2bf(float f) {
    unsigned u = __float_as_uint(f);
    u += 0x7fffu + ((u >> 16) & 1u);
    return (unsigned short)(u >> 16);
}
__device__ __forceinline__ float bf2f(unsigned short h) {
    return __uint_as_float(((unsigned)h) << 16);
}

// ---- cast x (fp32) -> xb (bf16), 2 elems/thread ----
__global__ __launch_bounds__(256) void cast_x(const float* __restrict__ x,
                                              unsigned int* __restrict__ xb) {
    int i = blockIdx.x * 256 + threadIdx.x;
    if (i >= Nn * Ff / 2) return;
    float2 v = ((const float2*)x)[i];
    xb[i] = (unsigned)f2bf(v.x) | ((unsigned)f2bf(v.y) << 16);
}

// ---- pack 9 weight matrices (root,W0,W1 per layer) into MFMA B-fragment order ----
// packed[(((m*8+c)*4+s)*64+l)*8+i] = W_m[k][n], k = s*32+(l>>4)*8+i, n = c*16+(l&15)
__global__ __launch_bounds__(256) void pack_w(const float* __restrict__ W1, const float* __restrict__ r1,
                                              const float* __restrict__ W2, const float* __restrict__ r2,
                                              const float* __restrict__ W3, const float* __restrict__ r3,
                                              unsigned short* __restrict__ wp) {
    int t = blockIdx.x * 256 + threadIdx.x;
    if (t >= 9 * 16384) return;
    int i = t & 7, l = (t >> 3) & 63, s = (t >> 9) & 3, c = (t >> 11) & 7, m = t >> 14;
    int k = s * 32 + ((l >> 4) << 3) + i;
    int n = (c << 4) + (l & 15);
    int q = m / 3, j = m % 3;
    const float* Ws[3] = {W1, W2, W3};
    const float* rs[3] = {r1, r2, r3};
    const float* src = (j == 0) ? rs[q] : (Ws[q] + (size_t)(j - 1) * Ff * Hh);
    wp[t] = f2bf(src[k * Hh + n]);
}

// ---- CSR build ----
__global__ __launch_bounds__(256) void count_edges(const int* __restrict__ ei,
                                                   const int* __restrict__ ea,
                                                   int* __restrict__ cnt) {
    int e = blockIdx.x * 256 + threadIdx.x;
    if (e >= Ee) return;
    int d = ei[Ee + e];
    int r = ea[e] & 1;
    atomicAdd(&cnt[r * Nn + d], 1);
}

__global__ __launch_bounds__(256) void scan_part(const int* __restrict__ cnt,
                                                 int* __restrict__ loc,
                                                 int* __restrict__ bsum) {
    __shared__ int wsum[4];
    int t = threadIdx.x, b = blockIdx.x;
    int base = b * 1024 + t * 4;
    int v[4], s = 0;
    for (int j = 0; j < 4; ++j) {
        int idx = base + j;
        v[j] = (idx < Nn) ? (cnt[idx] + cnt[Nn + idx]) : 0;
        s += v[j];
    }
    int lane = t & 63, w = t >> 6;
    int inc = s;
    for (int off = 1; off < 64; off <<= 1) {
        int y = __shfl_up(inc, off, 64);
        if (lane >= off) inc += y;
    }
    if (lane == 63) wsum[w] = inc;
    __syncthreads();
    int wo = 0;
    if (w > 0) wo += wsum[0];
    if (w > 1) wo += wsum[1];
    if (w > 2) wo += wsum[2];
    int ex = wo + inc - s;
    int run = ex;
    for (int j = 0; j < 4; ++j) {
        int idx = base + j;
        if (idx < Nn) loc[idx] = run;
        run += v[j];
    }
    if (t == 255) bsum[b] = wo + inc;
}

__global__ void scan_bsum(int* __restrict__ bsum, int nb) {
    __shared__ int lds[128];
    int t = threadIdx.x;
    int v = (t < nb) ? bsum[t] : 0;
    lds[t] = v;
    __syncthreads();
    for (int off = 1; off < 128; off <<= 1) {
        int y = (t >= off) ? lds[t - off] : 0;
        __syncthreads();
        lds[t] += y;
        __syncthreads();
    }
    if (t < nb) bsum[t] = lds[t] - v;  // exclusive
}

__global__ __launch_bounds__(256) void scan_add(int* __restrict__ rowstart,
                                                const int* __restrict__ bsum,
                                                int* __restrict__ cursor) {
    int i = blockIdx.x * 256 + threadIdx.x;
    if (i < Nn) {
        int vv = rowstart[i] + bsum[i >> 10];
        rowstart[i] = vv;
        cursor[i] = vv;
    } else if (i == Nn) {
        rowstart[Nn] = Ee;
    }
}

__global__ __launch_bounds__(256) void fill_csr(const int* __restrict__ ei,
                                                const int* __restrict__ ea,
                                                int* __restrict__ cursor,
                                                int* __restrict__ csr) {
    int e = blockIdx.x * 256 + threadIdx.x;
    if (e >= Ee) return;
    int s = ei[e];
    int d = ei[Ee + e];
    int r = ea[e] & 1;
    int pos = atomicAdd(&cursor[d], 1);
    csr[pos] = (s << 1) | r;
}

// ---- graph start offsets from sorted batch ----
__global__ __launch_bounds__(256) void graph_starts(const int* __restrict__ batch,
                                                    int* __restrict__ gstart) {
    int n = blockIdx.x * 256 + threadIdx.x;
    if (n > Nn) return;
    int bp = (n == 0) ? -1 : batch[n - 1];
    int bc = (n == Nn) ? Gg : batch[n];
    for (int g = bp + 1; g <= bc; ++g) gstart[g] = n;
}

// ---- fused GEMM: agg = x@root + b (fp32), h0 = x@W0 (bf16), h1 = x@W1 (bf16) ----
__global__ __launch_bounds__(256) void gemm3(const unsigned short* __restrict__ xb,
                                             const unsigned short* __restrict__ wl,
                                             const float* __restrict__ bias,
                                             float* __restrict__ agg,
                                             unsigned short* __restrict__ h0,
                                             unsigned short* __restrict__ h1) {
    int w = threadIdx.x >> 6;
    int lane = threadIdx.x & 63;
    int row0 = blockIdx.x * 64 + w * 16;
    int m = lane & 15;
    int ksel = lane >> 4;
    int node = row0 + m;

    bf16x8 a[4];
    if (node < Nn) {
        const unsigned short* xrow = xb + (size_t)node * Ff;
        for (int s = 0; s < 4; ++s)
            a[s] = *(const bf16x8*)(xrow + s * 32 + ksel * 8);
    } else {
        for (int s = 0; s < 4; ++s)
            for (int i = 0; i < 8; ++i) a[s][i] = 0;
    }

    int srow = ksel * 4;  // C/D: col = lane&15, row = (lane>>4)*4 + j
    for (int c24 = 0; c24 < 24; ++c24) {
        int mat = c24 >> 3, cb = c24 & 7;
        const unsigned short* wb = wl + ((size_t)(mat * 8 + cb)) * 2048;
        f32x4 acc = {0.f, 0.f, 0.f, 0.f};
        for (int s = 0; s < 4; ++s) {
            bf16x8 bfr = *(const bf16x8*)(wb + s * 512 + lane * 8);
            acc = __builtin_amdgcn_mfma_f32_16x16x32_bf16(a[s], bfr, acc, 0, 0, 0);
        }
        int col = cb * 16 + m;
        if (mat == 0) {
            float bv = bias[col];
            for (int j = 0; j < 4; ++j) {
                int rr = row0 + srow + j;
                if (rr < Nn) agg[(size_t)rr * Hh + col] = acc[j] + bv;
            }
        } else {
            unsigned short* hp = (mat == 1) ? h0 : h1;
            for (int j = 0; j < 4; ++j) {
                int rr = row0 + srow + j;
                if (rr < Nn) hp[(size_t)rr * Hh + col] = f2bf(acc[j]);
            }
        }
    }
}

// ---- aggregation: out[d] = relu(agg[d] + mean_r0 + mean_r1), one wave per dst ----
__global__ __launch_bounds__(256) void aggregate(const float* __restrict__ agg,
                                                 const unsigned short* __restrict__ h0,
                                                 const unsigned short* __restrict__ h1,
                                                 const int* __restrict__ csr,
                                                 const int* __restrict__ rowstart,
                                                 const int* __restrict__ cnt,
                                                 unsigned int* __restrict__ xout) {
    int d = blockIdx.x * 4 + (threadIdx.x >> 6);
    if (d >= Nn) return;
    int lane = threadIdx.x & 63;
    float a0 = 0.f, a1 = 0.f, b0 = 0.f, b1 = 0.f;
    int s = rowstart[d], e = rowstart[d + 1];
    for (int i = s; i < e; ++i) {
        int v = csr[i];
        int src = v >> 1;
        const unsigned short* hp = (v & 1) ? h1 : h0;
        unsigned u = *(const unsigned*)(hp + (size_t)src * Hh + lane * 2);
        float f0 = bf2f((unsigned short)(u & 0xffff));
        float f1 = bf2f((unsigned short)(u >> 16));
        if (v & 1) { b0 += f0; b1 += f1; }
        else       { a0 += f0; a1 += f1; }
    }
    float r0 = 1.f / fmaxf((float)cnt[d], 1.f);
    float r1 = 1.f / fmaxf((float)cnt[Nn + d], 1.f);
    float2 base = *(const float2*)(agg + (size_t)d * Hh + lane * 2);
    float o0 = fmaxf(base.x + a0 * r0 + b0 * r1, 0.f);
    float o1 = fmaxf(base.y + a1 * r0 + b1 * r1, 0.f);
    xout[d * (Hh / 2) + lane] = (unsigned)f2bf(o0) | ((unsigned)f2bf(o1) << 16);
}

// ---- pool + linear: one wave per graph ----
__global__ __launch_bounds__(256) void pool_linear(const unsigned int* __restrict__ xb,
                                                   const int* __restrict__ gstart,
                                                   const float* __restrict__ lin_w,
                                                   const float* __restrict__ lin_b,
                                                   float* __restrict__ out) {
    int g = blockIdx.x * 4 + (threadIdx.x >> 6);
    if (g >= Gg) return;
    int lane = threadIdx.x & 63;
    int s = gstart[g], e = gstart[g + 1];
    float a0 = 0.f, a1 = 0.f;
    for (int n = s; n < e; ++n) {
        unsigned u = xb[n * (Hh / 2) + lane];
        a0 += bf2f((unsigned short)(u & 0xffff));
        a1 += bf2f((unsigned short)(u >> 16));
    }
    float inv = 1.f / fmaxf((float)(e - s), 1.f);
    a0 *= inv; a1 *= inv;
    float p[Cc];
    int k0 = 2 * lane, k1 = 2 * lane + 1;
    for (int c = 0; c < Cc; ++c)
        p[c] = a0 * lin_w[k0 * Cc + c] + a1 * lin_w[k1 * Cc + c];
    for (int off = 32; off > 0; off >>= 1)
        for (int c = 0; c < Cc; ++c)
            p[c] += __shfl_down(p[c], off, 64);
    if (lane == 0)
        for (int c = 0; c < Cc; ++c) out[g * Cc + c] = p[c] + lin_b[c];
}

static inline size_t alignup(size_t v) { return (v + 255) & ~(size_t)255; }

extern "C" void kernel_launch(void* const* d_in, const int* in_sizes, int n_in,
                              void* d_out, int out_size, void* d_ws, size_t ws_size,
                              hipStream_t stream) {
    const float* x     = (const float*)d_in[0];
    const int*   ei    = (const int*)d_in[1];
    const int*   ea    = (const int*)d_in[2];
    const int*   batch = (const int*)d_in[3];
    const float* W1 = (const float*)d_in[4];
    const float* r1 = (const float*)d_in[5];
    const float* b1 = (const float*)d_in[6];
    const float* W2 = (const float*)d_in[7];
    const float* r2 = (const float*)d_in[8];
    const float* b2 = (const float*)d_in[9];
    const float* W3 = (const float*)d_in[10];
    const float* r3 = (const float*)d_in[11];
    const float* b3 = (const float*)d_in[12];
    const float* lin_w = (const float*)d_in[13];
    const float* lin_b = (const float*)d_in[14];
    float* out = (float*)d_out;

    char* p = (char*)d_ws;
    unsigned short* xb = (unsigned short*)p;   p += alignup((size_t)Nn * Ff * 2);
    unsigned short* h0 = (unsigned short*)p;   p += alignup((size_t)Nn * Hh * 2);
    unsigned short* h1 = (unsigned short*)p;   p += alignup((size_t)Nn * Hh * 2);
    float*          agg = (float*)p;           p += alignup((size_t)Nn * Hh * 4);
    unsigned short* wp = (unsigned short*)p;   p += alignup((size_t)9 * 16384 * 2);
    int* cnt      = (int*)p;                   p += alignup((size_t)2 * Nn * 4);
    int* rowstart = (int*)p;                   p += alignup((size_t)(Nn + 1) * 4);
    int* cursor   = (int*)p;                   p += alignup((size_t)Nn * 4);
    int* csr      = (int*)p;                   p += alignup((size_t)Ee * 4);
    int* bsum     = (int*)p;                   p += alignup(128 * 4);
    int* gstart   = (int*)p;                   p += alignup((size_t)(Gg + 1) * 4);

    hipMemsetAsync(cnt, 0, (size_t)2 * Nn * 4, stream);

    cast_x<<<(Nn * Ff / 2 + 255) / 256, 256, 0, stream>>>(x, (unsigned int*)xb);
    pack_w<<<(9 * 16384 + 255) / 256, 256, 0, stream>>>(W1, r1, W2, r2, W3, r3, wp);
    count_edges<<<(Ee + 255) / 256, 256, 0, stream>>>(ei, ea, cnt);
    graph_starts<<<(Nn + 1 + 255) / 256, 256, 0, stream>>>(batch, gstart);

    int nb = (Nn + 1023) / 1024;
    scan_part<<<nb, 256, 0, stream>>>(cnt, rowstart, bsum);
    scan_bsum<<<1, 128, 0, stream>>>(bsum, nb);
    scan_add<<<(Nn + 1 + 255) / 256, 256, 0, stream>>>(rowstart, bsum, cursor);
    fill_csr<<<(Ee + 255) / 256, 256, 0, stream>>>(ei, ea, cursor, csr);

    int gemm_grid = (Nn + 63) / 64;
    int agg_grid = (Nn + 3) / 4;

    // layer 1
    gemm3<<<gemm_grid, 256, 0, stream>>>(xb, wp + 0 * 3 * 16384, b1, agg, h0, h1);
    aggregate<<<agg_grid, 256, 0, stream>>>(agg, h0, h1, csr, rowstart, cnt, (unsigned int*)xb);
    // layer 2
    gemm3<<<gemm_grid, 256, 0, stream>>>(xb, wp + 1 * 3 * 16384, b2, agg, h0, h1);
    aggregate<<<agg_grid, 256, 0, stream>>>(agg, h0, h1, csr, rowstart, cnt, (unsigned int*)xb);
    // layer 3
    gemm3<<<gemm_grid, 256, 0, stream>>>(xb, wp + 2 * 3 * 16384, b3, agg, h0, h1);
    aggregate<<<agg_grid, 256, 0, stream>>>(agg, h0, h1, csr, rowstart, cnt, (unsigned int*)xb);

    pool_linear<<<(Gg + 3) / 4, 256, 0, stream>>>((const unsigned int*)xb, gstart, lin_w, lin_b, out);
}

// Round 2
// 630.714 us; speedup vs baseline: 1.4399x; 1.4399x over previous
//
#include <hip/hip_runtime.h>
#include <hip/hip_bf16.h>

#define Nn 100000
#define Ee 1600000
#define Ff 128
#define Hh 128
#define Cc 10
#define Gg 512

typedef short bf16x8 __attribute__((ext_vector_type(8)));
typedef float f32x4 __attribute__((ext_vector_type(4)));

__device__ __forceinline__ unsigned short f2bf(float f) {
    unsigned u = __float_as_uint(f);
    u += 0x7fffu + ((u >> 16) & 1u);
    return (unsigned short)(u >> 16);
}
__device__ __forceinline__ float lo16(unsigned u) { return __uint_as_float(u << 16); }
__device__ __forceinline__ float hi16(unsigned u) { return __uint_as_float(u & 0xffff0000u); }

// ---- cast x (fp32) -> xb (bf16), 2 elems/thread ----
__global__ __launch_bounds__(256) void cast_x(const float* __restrict__ x,
                                              unsigned int* __restrict__ xb) {
    int i = blockIdx.x * 256 + threadIdx.x;
    if (i >= Nn * Ff / 2) return;
    float2 v = ((const float2*)x)[i];
    xb[i] = (unsigned)f2bf(v.x) | ((unsigned)f2bf(v.y) << 16);
}

// ---- pack 9 weight matrices (root,W0,W1 per layer) into MFMA B-fragment order ----
// packed[(((m*8+c)*4+s)*64+l)*8+i] = W_m[k][n], k = s*32+(l>>4)*8+i, n = c*16+(l&15)
__global__ __launch_bounds__(256) void pack_w(const float* __restrict__ W1, const float* __restrict__ r1,
                                              const float* __restrict__ W2, const float* __restrict__ r2,
                                              const float* __restrict__ W3, const float* __restrict__ r3,
                                              unsigned short* __restrict__ wp) {
    int t = blockIdx.x * 256 + threadIdx.x;
    if (t >= 9 * 16384) return;
    int i = t & 7, l = (t >> 3) & 63, s = (t >> 9) & 3, c = (t >> 11) & 7, m = t >> 14;
    int k = s * 32 + ((l >> 4) << 3) + i;
    int n = (c << 4) + (l & 15);
    int q = m / 3, j = m % 3;
    const float* Ws[3] = {W1, W2, W3};
    const float* rs[3] = {r1, r2, r3};
    const float* src = (j == 0) ? rs[q] : (Ws[q] + (size_t)(j - 1) * Ff * Hh);
    wp[t] = f2bf(src[k * Hh + n]);
}

// ---- CSR build ----
__global__ __launch_bounds__(256) void count_edges(const int* __restrict__ ei,
                                                   const int* __restrict__ ea,
                                                   int* __restrict__ cnt) {
    int e = blockIdx.x * 256 + threadIdx.x;
    if (e >= Ee) return;
    int d = ei[Ee + e];
    int r = ea[e] & 1;
    atomicAdd(&cnt[r * Nn + d], 1);
}

__global__ __launch_bounds__(256) void scan_part(const int* __restrict__ cnt,
                                                 int* __restrict__ loc,
                                                 int* __restrict__ bsum) {
    __shared__ int wsum[4];
    int t = threadIdx.x, b = blockIdx.x;
    int base = b * 1024 + t * 4;
    int v[4], s = 0;
    for (int j = 0; j < 4; ++j) {
        int idx = base + j;
        v[j] = (idx < Nn) ? (cnt[idx] + cnt[Nn + idx]) : 0;
        s += v[j];
    }
    int lane = t & 63, w = t >> 6;
    int inc = s;
    for (int off = 1; off < 64; off <<= 1) {
        int y = __shfl_up(inc, off, 64);
        if (lane >= off) inc += y;
    }
    if (lane == 63) wsum[w] = inc;
    __syncthreads();
    int wo = 0;
    if (w > 0) wo += wsum[0];
    if (w > 1) wo += wsum[1];
    if (w > 2) wo += wsum[2];
    int ex = wo + inc - s;
    int run = ex;
    for (int j = 0; j < 4; ++j) {
        int idx = base + j;
        if (idx < Nn) loc[idx] = run;
        run += v[j];
    }
    if (t == 255) bsum[b] = wo + inc;
}

__global__ void scan_bsum(int* __restrict__ bsum, int nb) {
    __shared__ int lds[128];
    int t = threadIdx.x;
    int v = (t < nb) ? bsum[t] : 0;
    lds[t] = v;
    __syncthreads();
    for (int off = 1; off < 128; off <<= 1) {
        int y = (t >= off) ? lds[t - off] : 0;
        __syncthreads();
        lds[t] += y;
        __syncthreads();
    }
    if (t < nb) bsum[t] = lds[t] - v;  // exclusive
}

// rowstart[i] = global exclusive prefix; mid[i] = rowstart[i] + cnt_rel0[i];
// cursor[i] / cursor[Nn+i] = fill cursors for rel0 / rel1 regions
__global__ __launch_bounds__(256) void scan_add(int* __restrict__ rowstart,
                                                const int* __restrict__ bsum,
                                                const int* __restrict__ cnt,
                                                int* __restrict__ mid,
                                                int* __restrict__ cursor) {
    int i = blockIdx.x * 256 + threadIdx.x;
    if (i < Nn) {
        int base = rowstart[i] + bsum[i >> 10];
        rowstart[i] = base;
        int c0 = cnt[i];
        mid[i] = base + c0;
        cursor[i] = base;
        cursor[Nn + i] = base + c0;
    } else if (i == Nn) {
        rowstart[Nn] = Ee;
    }
}

__global__ __launch_bounds__(256) void fill_csr(const int* __restrict__ ei,
                                                const int* __restrict__ ea,
                                                int* __restrict__ cursor,
                                                int* __restrict__ csr) {
    int e = blockIdx.x * 256 + threadIdx.x;
    if (e >= Ee) return;
    int s = ei[e];
    int d = ei[Ee + e];
    int r = ea[e] & 1;
    int pos = atomicAdd(&cursor[r * Nn + d], 1);
    csr[pos] = s;
}

// ---- graph start offsets from sorted batch ----
__global__ __launch_bounds__(256) void graph_starts(const int* __restrict__ batch,
                                                    int* __restrict__ gstart) {
    int n = blockIdx.x * 256 + threadIdx.x;
    if (n > Nn) return;
    int bp = (n == 0) ? -1 : batch[n - 1];
    int bc = (n == Nn) ? Gg : batch[n];
    for (int g = bp + 1; g <= bc; ++g) gstart[g] = n;
}

// ---- fused GEMM: aggb = bf16(x@root + b), h0 = bf16(x@W0), h1 = bf16(x@W1) ----
// 32 rows per wave (2 row-tiles share each B fragment): halves weight re-reads.
__global__ __launch_bounds__(256) void gemm3(const unsigned short* __restrict__ xb,
                                             const unsigned short* __restrict__ wl,
                                             const float* __restrict__ bias,
                                             unsigned short* __restrict__ aggb,
                                             unsigned short* __restrict__ h0,
                                             unsigned short* __restrict__ h1) {
    int w = threadIdx.x >> 6;
    int lane = threadIdx.x & 63;
    int m = lane & 15;
    int ksel = lane >> 4;
    int row0 = blockIdx.x * 128 + w * 32;

    bf16x8 a[2][4];
    for (int rt = 0; rt < 2; ++rt) {
        int node = row0 + rt * 16 + m;
        if (node < Nn) {
            const unsigned short* xrow = xb + (size_t)node * Ff;
            for (int s = 0; s < 4; ++s)
                a[rt][s] = *(const bf16x8*)(xrow + s * 32 + ksel * 8);
        } else {
            for (int s = 0; s < 4; ++s)
                for (int i = 0; i < 8; ++i) a[rt][s][i] = 0;
        }
    }

    int srow = ksel * 4;  // C/D: col = lane&15, row = (lane>>4)*4 + j
    for (int c24 = 0; c24 < 24; ++c24) {
        int mat = c24 >> 3, cb = c24 & 7;
        const unsigned short* wb = wl + ((size_t)(mat * 8 + cb)) * 2048;
        bf16x8 bfr[4];
        for (int s = 0; s < 4; ++s)
            bfr[s] = *(const bf16x8*)(wb + s * 512 + lane * 8);
        int col = cb * 16 + m;
        for (int rt = 0; rt < 2; ++rt) {
            f32x4 acc = {0.f, 0.f, 0.f, 0.f};
            for (int s = 0; s < 4; ++s)
                acc = __builtin_amdgcn_mfma_f32_16x16x32_bf16(a[rt][s], bfr[s], acc, 0, 0, 0);
            int rbase = row0 + rt * 16 + srow;
            if (mat == 0) {
                float bv = bias[col];
                for (int j = 0; j < 4; ++j) {
                    int rr = rbase + j;
                    if (rr < Nn) aggb[(size_t)rr * Hh + col] = f2bf(acc[j] + bv);
                }
            } else {
                unsigned short* hp = (mat == 1) ? h0 : h1;
                for (int j = 0; j < 4; ++j) {
                    int rr = rbase + j;
                    if (rr < Nn) hp[(size_t)rr * Hh + col] = f2bf(acc[j]);
                }
            }
        }
    }
}

// ---- aggregation: out[d] = relu(aggb[d] + mean_r0 + mean_r1), one wave per dst ----
// rel-sorted CSR: [s,mid) rel0 srcs, [mid,e) rel1 srcs. Unroll x4 for MLP.
__global__ __launch_bounds__(256) void aggregate(const unsigned short* __restrict__ aggb,
                                                 const unsigned short* __restrict__ h0,
                                                 const unsigned short* __restrict__ h1,
                                                 const int* __restrict__ csr,
                                                 const int* __restrict__ rowstart,
                                                 const int* __restrict__ mid,
                                                 unsigned int* __restrict__ xout) {
    int d = blockIdx.x * 4 + (threadIdx.x >> 6);
    if (d >= Nn) return;
    int lane = threadIdx.x & 63;
    int col2 = lane * 2;
    int s = rowstart[d], md = mid[d], e = rowstart[d + 1];

    float a0 = 0.f, a1 = 0.f, b0 = 0.f, b1 = 0.f;

    int i = s;
    for (; i + 4 <= md; i += 4) {
        int p0 = csr[i], p1 = csr[i + 1], p2 = csr[i + 2], p3 = csr[i + 3];
        unsigned u0 = *(const unsigned*)(h0 + (size_t)p0 * Hh + col2);
        unsigned u1 = *(const unsigned*)(h0 + (size_t)p1 * Hh + col2);
        unsigned u2 = *(const unsigned*)(h0 + (size_t)p2 * Hh + col2);
        unsigned u3 = *(const unsigned*)(h0 + (size_t)p3 * Hh + col2);
        a0 += lo16(u0) + lo16(u1) + lo16(u2) + lo16(u3);
        a1 += hi16(u0) + hi16(u1) + hi16(u2) + hi16(u3);
    }
    for (; i < md; ++i) {
        unsigned u = *(const unsigned*)(h0 + (size_t)csr[i] * Hh + col2);
        a0 += lo16(u); a1 += hi16(u);
    }
    for (; i + 4 <= e; i += 4) {
        int p0 = csr[i], p1 = csr[i + 1], p2 = csr[i + 2], p3 = csr[i + 3];
        unsigned u0 = *(const unsigned*)(h1 + (size_t)p0 * Hh + col2);
        unsigned u1 = *(const unsigned*)(h1 + (size_t)p1 * Hh + col2);
        unsigned u2 = *(const unsigned*)(h1 + (size_t)p2 * Hh + col2);
        unsigned u3 = *(const unsigned*)(h1 + (size_t)p3 * Hh + col2);
        b0 += lo16(u0) + lo16(u1) + lo16(u2) + lo16(u3);
        b1 += hi16(u0) + hi16(u1) + hi16(u2) + hi16(u3);
    }
    for (; i < e; ++i) {
        unsigned u = *(const unsigned*)(h1 + (size_t)csr[i] * Hh + col2);
        b0 += lo16(u); b1 += hi16(u);
    }

    float inv0 = 1.f / fmaxf((float)(md - s), 1.f);
    float inv1 = 1.f / fmaxf((float)(e - md), 1.f);
    unsigned ub = *(const unsigned*)(aggb + (size_t)d * Hh + col2);
    float o0 = fmaxf(lo16(ub) + a0 * inv0 + b0 * inv1, 0.f);
    float o1 = fmaxf(hi16(ub) + a1 * inv0 + b1 * inv1, 0.f);
    xout[d * (Hh / 2) + lane] = (unsigned)f2bf(o0) | ((unsigned)f2bf(o1) << 16);
}

// ---- pool + linear: one wave per graph ----
__global__ __launch_bounds__(256) void pool_linear(const unsigned int* __restrict__ xb,
                                                   const int* __restrict__ gstart,
                                                   const float* __restrict__ lin_w,
                                                   const float* __restrict__ lin_b,
                                                   float* __restrict__ out) {
    int g = blockIdx.x * 4 + (threadIdx.x >> 6);
    if (g >= Gg) return;
    int lane = threadIdx.x & 63;
    int s = gstart[g], e = gstart[g + 1];
    float a0 = 0.f, a1 = 0.f;
    for (int n = s; n < e; ++n) {
        unsigned u = xb[n * (Hh / 2) + lane];
        a0 += lo16(u);
        a1 += hi16(u);
    }
    float inv = 1.f / fmaxf((float)(e - s), 1.f);
    a0 *= inv; a1 *= inv;
    float p[Cc];
    int k0 = 2 * lane, k1 = 2 * lane + 1;
    for (int c = 0; c < Cc; ++c)
        p[c] = a0 * lin_w[k0 * Cc + c] + a1 * lin_w[k1 * Cc + c];
    for (int off = 32; off > 0; off >>= 1)
        for (int c = 0; c < Cc; ++c)
            p[c] += __shfl_down(p[c], off, 64);
    if (lane == 0)
        for (int c = 0; c < Cc; ++c) out[g * Cc + c] = p[c] + lin_b[c];
}

static inline size_t alignup(size_t v) { return (v + 255) & ~(size_t)255; }

extern "C" void kernel_launch(void* const* d_in, const int* in_sizes, int n_in,
                              void* d_out, int out_size, void* d_ws, size_t ws_size,
                              hipStream_t stream) {
    const float* x     = (const float*)d_in[0];
    const int*   ei    = (const int*)d_in[1];
    const int*   ea    = (const int*)d_in[2];
    const int*   batch = (const int*)d_in[3];
    const float* W1 = (const float*)d_in[4];
    const float* r1 = (const float*)d_in[5];
    const float* b1 = (const float*)d_in[6];
    const float* W2 = (const float*)d_in[7];
    const float* r2 = (const float*)d_in[8];
    const float* b2 = (const float*)d_in[9];
    const float* W3 = (const float*)d_in[10];
    const float* r3 = (const float*)d_in[11];
    const float* b3 = (const float*)d_in[12];
    const float* lin_w = (const float*)d_in[13];
    const float* lin_b = (const float*)d_in[14];
    float* out = (float*)d_out;

    char* p = (char*)d_ws;
    unsigned short* xb  = (unsigned short*)p;  p += alignup((size_t)Nn * Ff * 2);
    unsigned short* h0  = (unsigned short*)p;  p += alignup((size_t)Nn * Hh * 2);
    unsigned short* h1  = (unsigned short*)p;  p += alignup((size_t)Nn * Hh * 2);
    unsigned short* aggb = (unsigned short*)p; p += alignup((size_t)Nn * Hh * 2);
    unsigned short* wp  = (unsigned short*)p;  p += alignup((size_t)9 * 16384 * 2);
    int* cnt      = (int*)p;                   p += alignup((size_t)2 * Nn * 4);
    int* rowstart = (int*)p;                   p += alignup((size_t)(Nn + 1) * 4);
    int* mid      = (int*)p;                   p += alignup((size_t)Nn * 4);
    int* cursor   = (int*)p;                   p += alignup((size_t)2 * Nn * 4);
    int* csr      = (int*)p;                   p += alignup((size_t)Ee * 4);
    int* bsum     = (int*)p;                   p += alignup(128 * 4);
    int* gstart   = (int*)p;                   p += alignup((size_t)(Gg + 1) * 4);

    hipMemsetAsync(cnt, 0, (size_t)2 * Nn * 4, stream);

    cast_x<<<(Nn * Ff / 2 + 255) / 256, 256, 0, stream>>>(x, (unsigned int*)xb);
    pack_w<<<(9 * 16384 + 255) / 256, 256, 0, stream>>>(W1, r1, W2, r2, W3, r3, wp);
    count_edges<<<(Ee + 255) / 256, 256, 0, stream>>>(ei, ea, cnt);
    graph_starts<<<(Nn + 1 + 255) / 256, 256, 0, stream>>>(batch, gstart);

    int nb = (Nn + 1023) / 1024;
    scan_part<<<nb, 256, 0, stream>>>(cnt, rowstart, bsum);
    scan_bsum<<<1, 128, 0, stream>>>(bsum, nb);
    scan_add<<<(Nn + 1 + 255) / 256, 256, 0, stream>>>(rowstart, bsum, cnt, mid, cursor);
    fill_csr<<<(Ee + 255) / 256, 256, 0, stream>>>(ei, ea, cursor, csr);

    int gemm_grid = (Nn + 127) / 128;
    int agg_grid = (Nn + 3) / 4;

    // layer 1
    gemm3<<<gemm_grid, 256, 0, stream>>>(xb, wp + 0 * 3 * 16384, b1, aggb, h0, h1);
    aggregate<<<agg_grid, 256, 0, stream>>>(aggb, h0, h1, csr, rowstart, mid, (unsigned int*)xb);
    // layer 2
    gemm3<<<gemm_grid, 256, 0, stream>>>(xb, wp + 1 * 3 * 16384, b2, aggb, h0, h1);
    aggregate<<<agg_grid, 256, 0, stream>>>(aggb, h0, h1, csr, rowstart, mid, (unsigned int*)xb);
    // layer 3
    gemm3<<<gemm_grid, 256, 0, stream>>>(xb, wp + 2 * 3 * 16384, b3, aggb, h0, h1);
    aggregate<<<agg_grid, 256, 0, stream>>>(aggb, h0, h1, csr, rowstart, mid, (unsigned int*)xb);

    pool_linear<<<(Gg + 3) / 4, 256, 0, stream>>>((const unsigned int*)xb, gstart, lin_w, lin_b, out);
}

// Round 3
// 591.030 us; speedup vs baseline: 1.5366x; 1.0671x over previous
//
#include <hip/hip_runtime.h>
#include <hip/hip_bf16.h>

#define Nn 100000
#define Ee 1600000
#define Ff 128
#define Hh 128
#define Cc 10
#define Gg 512
#define NCOH 4
#define SLICE ((Nn + NCOH - 1) / NCOH)

typedef short bf16x8 __attribute__((ext_vector_type(8)));
typedef float f32x4 __attribute__((ext_vector_type(4)));

__device__ __forceinline__ unsigned short f2bf(float f) {
    unsigned u = __float_as_uint(f);
    u += 0x7fffu + ((u >> 16) & 1u);
    return (unsigned short)(u >> 16);
}
__device__ __forceinline__ float bf2f(unsigned short h) {
    return __uint_as_float(((unsigned)h) << 16);
}
__device__ __forceinline__ unsigned pk2(float a, float b) {
    return (unsigned)f2bf(a) | ((unsigned)f2bf(b) << 16);
}

// ---- cast x (fp32) -> xb (bf16), 2 elems/thread ----
__global__ __launch_bounds__(256) void cast_x(const float* __restrict__ x,
                                              unsigned int* __restrict__ xb) {
    int i = blockIdx.x * 256 + threadIdx.x;
    if (i >= Nn * Ff / 2) return;
    float2 v = ((const float2*)x)[i];
    xb[i] = pk2(v.x, v.y);
}

// ---- pack 9 weight matrices (root,W0,W1 per layer) into MFMA B-fragment order ----
// packed[(((m*8+c)*4+s)*64+l)*8+i] = W_m[k][n], k = s*32+(l>>4)*8+i, n = c*16+(l&15)
__global__ __launch_bounds__(256) void pack_w(const float* __restrict__ W1, const float* __restrict__ r1,
                                              const float* __restrict__ W2, const float* __restrict__ r2,
                                              const float* __restrict__ W3, const float* __restrict__ r3,
                                              unsigned short* __restrict__ wp) {
    int t = blockIdx.x * 256 + threadIdx.x;
    if (t >= 9 * 16384) return;
    int i = t & 7, l = (t >> 3) & 63, s = (t >> 9) & 3, c = (t >> 11) & 7, m = t >> 14;
    int k = s * 32 + ((l >> 4) << 3) + i;
    int n = (c << 4) + (l & 15);
    int q = m / 3, j = m % 3;
    const float* Ws[3] = {W1, W2, W3};
    const float* rs[3] = {r1, r2, r3};
    const float* src = (j == 0) ? rs[q] : (Ws[q] + (size_t)(j - 1) * Ff * Hh);
    wp[t] = f2bf(src[k * Hh + n]);
}

// ---- CSR build ----
__global__ __launch_bounds__(256) void count_edges(const int* __restrict__ ei,
                                                   const int* __restrict__ ea,
                                                   int* __restrict__ cnt) {
    int e = blockIdx.x * 256 + threadIdx.x;
    if (e >= Ee) return;
    int d = ei[Ee + e];
    int r = ea[e] & 1;
    atomicAdd(&cnt[r * Nn + d], 1);
}

__global__ __launch_bounds__(256) void scan_part(const int* __restrict__ cnt,
                                                 int* __restrict__ loc,
                                                 int* __restrict__ bsum) {
    __shared__ int wsum[4];
    int t = threadIdx.x, b = blockIdx.x;
    int base = b * 1024 + t * 4;
    int v[4], s = 0;
    for (int j = 0; j < 4; ++j) {
        int idx = base + j;
        v[j] = (idx < Nn) ? (cnt[idx] + cnt[Nn + idx]) : 0;
        s += v[j];
    }
    int lane = t & 63, w = t >> 6;
    int inc = s;
    for (int off = 1; off < 64; off <<= 1) {
        int y = __shfl_up(inc, off, 64);
        if (lane >= off) inc += y;
    }
    if (lane == 63) wsum[w] = inc;
    __syncthreads();
    int wo = 0;
    if (w > 0) wo += wsum[0];
    if (w > 1) wo += wsum[1];
    if (w > 2) wo += wsum[2];
    int ex = wo + inc - s;
    int run = ex;
    for (int j = 0; j < 4; ++j) {
        int idx = base + j;
        if (idx < Nn) loc[idx] = run;
        run += v[j];
    }
    if (t == 255) bsum[b] = wo + inc;
}

__global__ void scan_bsum(int* __restrict__ bsum, int nb) {
    __shared__ int lds[128];
    int t = threadIdx.x;
    int v = (t < nb) ? bsum[t] : 0;
    lds[t] = v;
    __syncthreads();
    for (int off = 1; off < 128; off <<= 1) {
        int y = (t >= off) ? lds[t - off] : 0;
        __syncthreads();
        lds[t] += y;
        __syncthreads();
    }
    if (t < nb) bsum[t] = lds[t] - v;  // exclusive
}

// rowstart[i] = global exclusive prefix; mid[i] = rowstart[i] + cnt_rel0[i];
// cursor[i] / cursor[Nn+i] = fill cursors for rel0 / rel1 regions
__global__ __launch_bounds__(256) void scan_add(int* __restrict__ rowstart,
                                                const int* __restrict__ bsum,
                                                const int* __restrict__ cnt,
                                                int* __restrict__ mid,
                                                int* __restrict__ cursor) {
    int i = blockIdx.x * 256 + threadIdx.x;
    if (i < Nn) {
        int base = rowstart[i] + bsum[i >> 10];
        rowstart[i] = base;
        int c0 = cnt[i];
        mid[i] = base + c0;
        cursor[i] = base;
        cursor[Nn + i] = base + c0;
    } else if (i == Nn) {
        rowstart[Nn] = Ee;
    }
}

// ---- cohort-sliced CSR fill: cohort c handles dst slice c; writes stay L2-resident ----
__global__ __launch_bounds__(256) void fill_csr(const int* __restrict__ ei,
                                                const int* __restrict__ ea,
                                                int* __restrict__ cursor,
                                                int* __restrict__ csr) {
    int coh = blockIdx.x & (NCOH - 1);
    int blk = blockIdx.x >> 2;
    int nblk = gridDim.x >> 2;
    int lo = coh * SLICE;
    int hi = lo + SLICE;
    for (int e = blk * 256 + threadIdx.x; e < Ee; e += nblk * 256) {
        int d = ei[Ee + e];
        if (d >= lo && d < hi) {
            int s = ei[e];
            int r = ea[e] & 1;
            int pos = atomicAdd(&cursor[r * Nn + d], 1);
            csr[pos] = s;
        }
    }
}

// ---- graph start offsets from sorted batch ----
__global__ __launch_bounds__(256) void graph_starts(const int* __restrict__ batch,
                                                    int* __restrict__ gstart) {
    int n = blockIdx.x * 256 + threadIdx.x;
    if (n > Nn) return;
    int bp = (n == 0) ? -1 : batch[n - 1];
    int bc = (n == Nn) ? Gg : batch[n];
    for (int g = bp + 1; g <= bc; ++g) gstart[g] = n;
}

// ---- aggregation: xg0[d] = mean_{r0} xb[src], xg1[d] = mean_{r1} xb[src] ----
// Half-wave = one row (32 lanes x 8B): 2 edges per gather instruction, unroll x4.
__global__ __launch_bounds__(256) void aggregate(const unsigned short* __restrict__ xb,
                                                 const int* __restrict__ csr,
                                                 const int* __restrict__ rowstart,
                                                 const int* __restrict__ mid,
                                                 unsigned int* __restrict__ xg0,
                                                 unsigned int* __restrict__ xg1) {
    int d = blockIdx.x * 4 + (threadIdx.x >> 6);
    if (d >= Nn) return;
    int lane = threadIdx.x & 63;
    int h = lane >> 5;            // which edge of the pair
    int c4 = (lane & 31) * 4;     // this lane's 4 bf16 columns
    int s = rowstart[d], md = mid[d], e = rowstart[d + 1];

    float A0[4] = {0.f, 0.f, 0.f, 0.f};
    float A1[4] = {0.f, 0.f, 0.f, 0.f};

    int i = s;
    // rel 0: [s, md)
    for (; i + 8 <= md; i += 8) {
        int e0 = csr[i + h], e1 = csr[i + 2 + h], e2 = csr[i + 4 + h], e3 = csr[i + 6 + h];
        ushort4 v0 = *(const ushort4*)(xb + (size_t)e0 * Hh + c4);
        ushort4 v1 = *(const ushort4*)(xb + (size_t)e1 * Hh + c4);
        ushort4 v2 = *(const ushort4*)(xb + (size_t)e2 * Hh + c4);
        ushort4 v3 = *(const ushort4*)(xb + (size_t)e3 * Hh + c4);
        A0[0] += bf2f(v0.x) + bf2f(v1.x) + bf2f(v2.x) + bf2f(v3.x);
        A0[1] += bf2f(v0.y) + bf2f(v1.y) + bf2f(v2.y) + bf2f(v3.y);
        A0[2] += bf2f(v0.z) + bf2f(v1.z) + bf2f(v2.z) + bf2f(v3.z);
        A0[3] += bf2f(v0.w) + bf2f(v1.w) + bf2f(v2.w) + bf2f(v3.w);
    }
    for (; i + 2 <= md; i += 2) {
        int e0 = csr[i + h];
        ushort4 v = *(const ushort4*)(xb + (size_t)e0 * Hh + c4);
        A0[0] += bf2f(v.x); A0[1] += bf2f(v.y); A0[2] += bf2f(v.z); A0[3] += bf2f(v.w);
    }
    if (i < md && h == 0) {
        ushort4 v = *(const ushort4*)(xb + (size_t)csr[i] * Hh + c4);
        A0[0] += bf2f(v.x); A0[1] += bf2f(v.y); A0[2] += bf2f(v.z); A0[3] += bf2f(v.w);
    }
    // rel 1: [md, e)
    i = md;
    for (; i + 8 <= e; i += 8) {
        int e0 = csr[i + h], e1 = csr[i + 2 + h], e2 = csr[i + 4 + h], e3 = csr[i + 6 + h];
        ushort4 v0 = *(const ushort4*)(xb + (size_t)e0 * Hh + c4);
        ushort4 v1 = *(const ushort4*)(xb + (size_t)e1 * Hh + c4);
        ushort4 v2 = *(const ushort4*)(xb + (size_t)e2 * Hh + c4);
        ushort4 v3 = *(const ushort4*)(xb + (size_t)e3 * Hh + c4);
        A1[0] += bf2f(v0.x) + bf2f(v1.x) + bf2f(v2.x) + bf2f(v3.x);
        A1[1] += bf2f(v0.y) + bf2f(v1.y) + bf2f(v2.y) + bf2f(v3.y);
        A1[2] += bf2f(v0.z) + bf2f(v1.z) + bf2f(v2.z) + bf2f(v3.z);
        A1[3] += bf2f(v0.w) + bf2f(v1.w) + bf2f(v2.w) + bf2f(v3.w);
    }
    for (; i + 2 <= e; i += 2) {
        int e0 = csr[i + h];
        ushort4 v = *(const ushort4*)(xb + (size_t)e0 * Hh + c4);
        A1[0] += bf2f(v.x); A1[1] += bf2f(v.y); A1[2] += bf2f(v.z); A1[3] += bf2f(v.w);
    }
    if (i < e && h == 0) {
        ushort4 v = *(const ushort4*)(xb + (size_t)csr[i] * Hh + c4);
        A1[0] += bf2f(v.x); A1[1] += bf2f(v.y); A1[2] += bf2f(v.z); A1[3] += bf2f(v.w);
    }

    // combine the two half-wave partial sums
    #pragma unroll
    for (int j = 0; j < 4; ++j) {
        A0[j] += __shfl_xor(A0[j], 32);
        A1[j] += __shfl_xor(A1[j], 32);
    }

    if (h == 0) {
        float i0 = 1.f / fmaxf((float)(md - s), 1.f);
        float i1 = 1.f / fmaxf((float)(e - md), 1.f);
        uint2 p0, p1;
        p0.x = pk2(A0[0] * i0, A0[1] * i0);
        p0.y = pk2(A0[2] * i0, A0[3] * i0);
        p1.x = pk2(A1[0] * i1, A1[1] * i1);
        p1.y = pk2(A1[2] * i1, A1[3] * i1);
        *(uint2*)(xg0 + (size_t)d * (Hh / 2) + (lane & 31) * 2) = p0;
        *(uint2*)(xg1 + (size_t)d * (Hh / 2) + (lane & 31) * 2) = p1;
    }
}

// ---- fused GEMM: out = relu(xb@root + xg0@W0 + xg1@W1 + b), bf16 out ----
__global__ __launch_bounds__(256) void gemm_fused(const unsigned short* __restrict__ x0,
                                                  const unsigned short* __restrict__ xg0,
                                                  const unsigned short* __restrict__ xg1,
                                                  const unsigned short* __restrict__ wl,
                                                  const float* __restrict__ bias,
                                                  unsigned short* __restrict__ out) {
    int w = threadIdx.x >> 6, lane = threadIdx.x & 63;
    int m = lane & 15, ksel = lane >> 4;
    int row0 = blockIdx.x * 128 + w * 32;

    const unsigned short* srcs[3] = {x0, xg0, xg1};
    bf16x8 a[2][3][4];
    #pragma unroll
    for (int rt = 0; rt < 2; ++rt) {
        int node = row0 + rt * 16 + m;
        #pragma unroll
        for (int mat = 0; mat < 3; ++mat) {
            const unsigned short* xrow = srcs[mat] + (size_t)node * Ff;
            #pragma unroll
            for (int s = 0; s < 4; ++s) {
                if (node < Nn) {
                    a[rt][mat][s] = *(const bf16x8*)(xrow + s * 32 + ksel * 8);
                } else {
                    #pragma unroll
                    for (int q = 0; q < 8; ++q) a[rt][mat][s][q] = 0;
                }
            }
        }
    }

    bool ev = (lane & 1) == 0;
    int j0 = ev ? 0 : 2;

    for (int cb = 0; cb < 8; ++cb) {
        f32x4 acc0 = {0.f, 0.f, 0.f, 0.f};
        f32x4 acc1 = {0.f, 0.f, 0.f, 0.f};
        #pragma unroll
        for (int mat = 0; mat < 3; ++mat) {
            #pragma unroll
            for (int s = 0; s < 4; ++s) {
                bf16x8 bfr = *(const bf16x8*)(wl + ((size_t)((mat * 8 + cb) * 4 + s)) * 512 + lane * 8);
                acc0 = __builtin_amdgcn_mfma_f32_16x16x32_bf16(a[0][mat][s], bfr, acc0, 0, 0, 0);
                acc1 = __builtin_amdgcn_mfma_f32_16x16x32_bf16(a[1][mat][s], bfr, acc1, 0, 0, 0);
            }
        }
        int col = cb * 16 + m;
        float bv = bias[col];
        int colb = col & ~1;
        #pragma unroll
        for (int rt = 0; rt < 2; ++rt) {
            f32x4 ac = rt ? acc1 : acc0;
            float o[4], po[4];
            #pragma unroll
            for (int j = 0; j < 4; ++j) o[j] = fmaxf(ac[j] + bv, 0.f);
            #pragma unroll
            for (int j = 0; j < 4; ++j) po[j] = __shfl_xor(o[j], 1);
            unsigned w0 = ev ? pk2(o[j0], 0.f)     : pk2(po[j0], 0.f);
            // build full words: lo = even col value, hi = odd col value
            unsigned pkw0 = ev ? ((unsigned)f2bf(o[j0])     | ((unsigned)f2bf(po[j0])     << 16))
                               : ((unsigned)f2bf(po[j0])    | ((unsigned)f2bf(o[j0])      << 16));
            unsigned pkw1 = ev ? ((unsigned)f2bf(o[j0 + 1]) | ((unsigned)f2bf(po[j0 + 1]) << 16))
                               : ((unsigned)f2bf(po[j0 + 1])| ((unsigned)f2bf(o[j0 + 1])  << 16));
            (void)w0;
            int rbase = row0 + rt * 16 + ksel * 4;
            int rr0 = rbase + j0, rr1 = rbase + j0 + 1;
            if (rr0 < Nn) *(unsigned*)(out + (size_t)rr0 * Hh + colb) = pkw0;
            if (rr1 < Nn) *(unsigned*)(out + (size_t)rr1 * Hh + colb) = pkw1;
        }
    }
}

// ---- pool + linear: one wave per graph ----
__global__ __launch_bounds__(256) void pool_linear(const unsigned int* __restrict__ xb,
                                                   const int* __restrict__ gstart,
                                                   const float* __restrict__ lin_w,
                                                   const float* __restrict__ lin_b,
                                                   float* __restrict__ out) {
    int g = blockIdx.x * 4 + (threadIdx.x >> 6);
    if (g >= Gg) return;
    int lane = threadIdx.x & 63;
    int s = gstart[g], e = gstart[g + 1];
    float a0 = 0.f, a1 = 0.f;
    for (int n = s; n < e; ++n) {
        unsigned u = xb[(size_t)n * (Hh / 2) + lane];
        a0 += __uint_as_float(u << 16);
        a1 += __uint_as_float(u & 0xffff0000u);
    }
    float inv = 1.f / fmaxf((float)(e - s), 1.f);
    a0 *= inv; a1 *= inv;
    float p[Cc];
    int k0 = 2 * lane, k1 = 2 * lane + 1;
    for (int c = 0; c < Cc; ++c)
        p[c] = a0 * lin_w[k0 * Cc + c] + a1 * lin_w[k1 * Cc + c];
    for (int off = 32; off > 0; off >>= 1)
        for (int c = 0; c < Cc; ++c)
            p[c] += __shfl_down(p[c], off, 64);
    if (lane == 0)
        for (int c = 0; c < Cc; ++c) out[g * Cc + c] = p[c] + lin_b[c];
}

static inline size_t alignup(size_t v) { return (v + 255) & ~(size_t)255; }

extern "C" void kernel_launch(void* const* d_in, const int* in_sizes, int n_in,
                              void* d_out, int out_size, void* d_ws, size_t ws_size,
                              hipStream_t stream) {
    const float* x     = (const float*)d_in[0];
    const int*   ei    = (const int*)d_in[1];
    const int*   ea    = (const int*)d_in[2];
    const int*   batch = (const int*)d_in[3];
    const float* W1 = (const float*)d_in[4];
    const float* r1 = (const float*)d_in[5];
    const float* b1 = (const float*)d_in[6];
    const float* W2 = (const float*)d_in[7];
    const float* r2 = (const float*)d_in[8];
    const float* b2 = (const float*)d_in[9];
    const float* W3 = (const float*)d_in[10];
    const float* r3 = (const float*)d_in[11];
    const float* b3 = (const float*)d_in[12];
    const float* lin_w = (const float*)d_in[13];
    const float* lin_b = (const float*)d_in[14];
    float* out = (float*)d_out;

    char* p = (char*)d_ws;
    unsigned short* xbA = (unsigned short*)p;  p += alignup((size_t)Nn * Hh * 2);
    unsigned short* xbB = (unsigned short*)p;  p += alignup((size_t)Nn * Hh * 2);
    unsigned short* xg0 = (unsigned short*)p;  p += alignup((size_t)Nn * Hh * 2);
    unsigned short* xg1 = (unsigned short*)p;  p += alignup((size_t)Nn * Hh * 2);
    unsigned short* wp  = (unsigned short*)p;  p += alignup((size_t)9 * 16384 * 2);
    int* cnt      = (int*)p;                   p += alignup((size_t)2 * Nn * 4);
    int* rowstart = (int*)p;                   p += alignup((size_t)(Nn + 1) * 4);
    int* mid      = (int*)p;                   p += alignup((size_t)Nn * 4);
    int* cursor   = (int*)p;                   p += alignup((size_t)2 * Nn * 4);
    int* csr      = (int*)p;                   p += alignup((size_t)Ee * 4);
    int* bsum     = (int*)p;                   p += alignup(128 * 4);
    int* gstart   = (int*)p;                   p += alignup((size_t)(Gg + 1) * 4);

    hipMemsetAsync(cnt, 0, (size_t)2 * Nn * 4, stream);

    cast_x<<<(Nn * Ff / 2 + 255) / 256, 256, 0, stream>>>(x, (unsigned int*)xbA);
    pack_w<<<(9 * 16384 + 255) / 256, 256, 0, stream>>>(W1, r1, W2, r2, W3, r3, wp);
    count_edges<<<(Ee + 255) / 256, 256, 0, stream>>>(ei, ea, cnt);
    graph_starts<<<(Nn + 1 + 255) / 256, 256, 0, stream>>>(batch, gstart);

    int nb = (Nn + 1023) / 1024;
    scan_part<<<nb, 256, 0, stream>>>(cnt, rowstart, bsum);
    scan_bsum<<<1, 128, 0, stream>>>(bsum, nb);
    scan_add<<<(Nn + 1 + 255) / 256, 256, 0, stream>>>(rowstart, bsum, cnt, mid, cursor);
    fill_csr<<<4096, 256, 0, stream>>>(ei, ea, cursor, csr);

    int gemm_grid = (Nn + 127) / 128;
    int agg_grid = (Nn + 3) / 4;

    // layer 1: xbA -> xbB
    aggregate<<<agg_grid, 256, 0, stream>>>(xbA, csr, rowstart, mid, (unsigned int*)xg0, (unsigned int*)xg1);
    gemm_fused<<<gemm_grid, 256, 0, stream>>>(xbA, xg0, xg1, wp + 0 * 3 * 16384, b1, xbB);
    // layer 2: xbB -> xbA
    aggregate<<<agg_grid, 256, 0, stream>>>(xbB, csr, rowstart, mid, (unsigned int*)xg0, (unsigned int*)xg1);
    gemm_fused<<<gemm_grid, 256, 0, stream>>>(xbB, xg0, xg1, wp + 1 * 3 * 16384, b2, xbA);
    // layer 3: xbA -> xbB
    aggregate<<<agg_grid, 256, 0, stream>>>(xbA, csr, rowstart, mid, (unsigned int*)xg0, (unsigned int*)xg1);
    gemm_fused<<<gemm_grid, 256, 0, stream>>>(xbA, xg0, xg1, wp + 2 * 3 * 16384, b3, xbB);

    pool_linear<<<(Gg + 3) / 4, 256, 0, stream>>>((const unsigned int*)xbB, gstart, lin_w, lin_b, out);
}

// Round 4
// 590.576 us; speedup vs baseline: 1.5377x; 1.0008x over previous
//
#include <hip/hip_runtime.h>
#include <hip/hip_bf16.h>

#define Nn 100000
#define Ee 1600000
#define Ff 128
#define Hh 128
#define Cc 10
#define Gg 512
#define NCOH 4
#define SLICE ((Nn + NCOH - 1) / NCOH)

typedef short bf16x8 __attribute__((ext_vector_type(8)));
typedef float f32x4 __attribute__((ext_vector_type(4)));

__device__ __forceinline__ unsigned short f2bf(float f) {
    unsigned u = __float_as_uint(f);
    u += 0x7fffu + ((u >> 16) & 1u);
    return (unsigned short)(u >> 16);
}
__device__ __forceinline__ float bf2f(unsigned short h) {
    return __uint_as_float(((unsigned)h) << 16);
}
__device__ __forceinline__ unsigned pk2(float a, float b) {
    return (unsigned)f2bf(a) | ((unsigned)f2bf(b) << 16);
}

// ---- cast x (fp32) -> xb (bf16), 2 elems/thread ----
__global__ __launch_bounds__(256) void cast_x(const float* __restrict__ x,
                                              unsigned int* __restrict__ xb) {
    int i = blockIdx.x * 256 + threadIdx.x;
    if (i >= Nn * Ff / 2) return;
    float2 v = ((const float2*)x)[i];
    xb[i] = pk2(v.x, v.y);
}

// ---- pack 9 weight matrices (root,W0,W1 per layer) into MFMA B-fragment order ----
// packed[(((m*8+c)*4+s)*64+l)*8+i] = W_m[k][n], k = s*32+(l>>4)*8+i, n = c*16+(l&15)
__global__ __launch_bounds__(256) void pack_w(const float* __restrict__ W1, const float* __restrict__ r1,
                                              const float* __restrict__ W2, const float* __restrict__ r2,
                                              const float* __restrict__ W3, const float* __restrict__ r3,
                                              unsigned short* __restrict__ wp) {
    int t = blockIdx.x * 256 + threadIdx.x;
    if (t >= 9 * 16384) return;
    int i = t & 7, l = (t >> 3) & 63, s = (t >> 9) & 3, c = (t >> 11) & 7, m = t >> 14;
    int k = s * 32 + ((l >> 4) << 3) + i;
    int n = (c << 4) + (l & 15);
    int q = m / 3, j = m % 3;
    const float* Ws[3] = {W1, W2, W3};
    const float* rs[3] = {r1, r2, r3};
    const float* src = (j == 0) ? rs[q] : (Ws[q] + (size_t)(j - 1) * Ff * Hh);
    wp[t] = f2bf(src[k * Hh + n]);
}

// ---- CSR build ----
__global__ __launch_bounds__(256) void count_edges(const int* __restrict__ ei,
                                                   const int* __restrict__ ea,
                                                   int* __restrict__ cnt) {
    int e = blockIdx.x * 256 + threadIdx.x;
    if (e >= Ee) return;
    int d = ei[Ee + e];
    int r = ea[e] & 1;
    atomicAdd(&cnt[r * Nn + d], 1);
}

__global__ __launch_bounds__(256) void scan_part(const int* __restrict__ cnt,
                                                 int* __restrict__ loc,
                                                 int* __restrict__ bsum) {
    __shared__ int wsum[4];
    int t = threadIdx.x, b = blockIdx.x;
    int base = b * 1024 + t * 4;
    int v[4], s = 0;
    for (int j = 0; j < 4; ++j) {
        int idx = base + j;
        v[j] = (idx < Nn) ? (cnt[idx] + cnt[Nn + idx]) : 0;
        s += v[j];
    }
    int lane = t & 63, w = t >> 6;
    int inc = s;
    for (int off = 1; off < 64; off <<= 1) {
        int y = __shfl_up(inc, off, 64);
        if (lane >= off) inc += y;
    }
    if (lane == 63) wsum[w] = inc;
    __syncthreads();
    int wo = 0;
    if (w > 0) wo += wsum[0];
    if (w > 1) wo += wsum[1];
    if (w > 2) wo += wsum[2];
    int ex = wo + inc - s;
    int run = ex;
    for (int j = 0; j < 4; ++j) {
        int idx = base + j;
        if (idx < Nn) loc[idx] = run;
        run += v[j];
    }
    if (t == 255) bsum[b] = wo + inc;
}

__global__ void scan_bsum(int* __restrict__ bsum, int nb) {
    __shared__ int lds[128];
    int t = threadIdx.x;
    int v = (t < nb) ? bsum[t] : 0;
    lds[t] = v;
    __syncthreads();
    for (int off = 1; off < 128; off <<= 1) {
        int y = (t >= off) ? lds[t - off] : 0;
        __syncthreads();
        lds[t] += y;
        __syncthreads();
    }
    if (t < nb) bsum[t] = lds[t] - v;  // exclusive
}

// rowstart[i] = global exclusive prefix; mid[i] = rowstart[i] + cnt_rel0[i];
// cursor[i] / cursor[Nn+i] = fill cursors for rel0 / rel1 regions
__global__ __launch_bounds__(256) void scan_add(int* __restrict__ rowstart,
                                                const int* __restrict__ bsum,
                                                const int* __restrict__ cnt,
                                                int* __restrict__ mid,
                                                int* __restrict__ cursor) {
    int i = blockIdx.x * 256 + threadIdx.x;
    if (i < Nn) {
        int base = rowstart[i] + bsum[i >> 10];
        rowstart[i] = base;
        int c0 = cnt[i];
        mid[i] = base + c0;
        cursor[i] = base;
        cursor[Nn + i] = base + c0;
    } else if (i == Nn) {
        rowstart[Nn] = Ee;
    }
}

// ---- cohort-sliced CSR fill: cohort c handles dst slice c; writes stay L2-resident ----
__global__ __launch_bounds__(256) void fill_csr(const int* __restrict__ ei,
                                                const int* __restrict__ ea,
                                                int* __restrict__ cursor,
                                                int* __restrict__ csr) {
    int coh = blockIdx.x & (NCOH - 1);
    int blk = blockIdx.x >> 2;
    int nblk = gridDim.x >> 2;
    int lo = coh * SLICE;
    int hi = lo + SLICE;
    for (int e = blk * 256 + threadIdx.x; e < Ee; e += nblk * 256) {
        int d = ei[Ee + e];
        if (d >= lo && d < hi) {
            int s = ei[e];
            int r = ea[e] & 1;
            int pos = atomicAdd(&cursor[r * Nn + d], 1);
            csr[pos] = s;
        }
    }
}

// ---- graph start offsets from sorted batch ----
__global__ __launch_bounds__(256) void graph_starts(const int* __restrict__ batch,
                                                    int* __restrict__ gstart) {
    int n = blockIdx.x * 256 + threadIdx.x;
    if (n > Nn) return;
    int bp = (n == 0) ? -1 : batch[n - 1];
    int bc = (n == Nn) ? Gg : batch[n];
    for (int g = bp + 1; g <= bc; ++g) gstart[g] = n;
}

// ---- aggregation: xg0[d] = mean_{r0} xb[src], xg1[d] = mean_{r1} xb[src] ----
// Half-wave = one row (32 lanes x 8B): 2 edges per gather instruction, unroll x4.
__global__ __launch_bounds__(256) void aggregate(const unsigned short* __restrict__ xb,
                                                 const int* __restrict__ csr,
                                                 const int* __restrict__ rowstart,
                                                 const int* __restrict__ mid,
                                                 unsigned int* __restrict__ xg0,
                                                 unsigned int* __restrict__ xg1) {
    int d = blockIdx.x * 4 + (threadIdx.x >> 6);
    if (d >= Nn) return;
    int lane = threadIdx.x & 63;
    int h = lane >> 5;            // which edge of the pair
    int c4 = (lane & 31) * 4;     // this lane's 4 bf16 columns
    int s = rowstart[d], md = mid[d], e = rowstart[d + 1];

    float A0[4] = {0.f, 0.f, 0.f, 0.f};
    float A1[4] = {0.f, 0.f, 0.f, 0.f};

    int i = s;
    // rel 0: [s, md)
    for (; i + 8 <= md; i += 8) {
        int e0 = csr[i + h], e1 = csr[i + 2 + h], e2 = csr[i + 4 + h], e3 = csr[i + 6 + h];
        ushort4 v0 = *(const ushort4*)(xb + (size_t)e0 * Hh + c4);
        ushort4 v1 = *(const ushort4*)(xb + (size_t)e1 * Hh + c4);
        ushort4 v2 = *(const ushort4*)(xb + (size_t)e2 * Hh + c4);
        ushort4 v3 = *(const ushort4*)(xb + (size_t)e3 * Hh + c4);
        A0[0] += bf2f(v0.x) + bf2f(v1.x) + bf2f(v2.x) + bf2f(v3.x);
        A0[1] += bf2f(v0.y) + bf2f(v1.y) + bf2f(v2.y) + bf2f(v3.y);
        A0[2] += bf2f(v0.z) + bf2f(v1.z) + bf2f(v2.z) + bf2f(v3.z);
        A0[3] += bf2f(v0.w) + bf2f(v1.w) + bf2f(v2.w) + bf2f(v3.w);
    }
    for (; i + 2 <= md; i += 2) {
        int e0 = csr[i + h];
        ushort4 v = *(const ushort4*)(xb + (size_t)e0 * Hh + c4);
        A0[0] += bf2f(v.x); A0[1] += bf2f(v.y); A0[2] += bf2f(v.z); A0[3] += bf2f(v.w);
    }
    if (i < md && h == 0) {
        ushort4 v = *(const ushort4*)(xb + (size_t)csr[i] * Hh + c4);
        A0[0] += bf2f(v.x); A0[1] += bf2f(v.y); A0[2] += bf2f(v.z); A0[3] += bf2f(v.w);
    }
    // rel 1: [md, e)
    i = md;
    for (; i + 8 <= e; i += 8) {
        int e0 = csr[i + h], e1 = csr[i + 2 + h], e2 = csr[i + 4 + h], e3 = csr[i + 6 + h];
        ushort4 v0 = *(const ushort4*)(xb + (size_t)e0 * Hh + c4);
        ushort4 v1 = *(const ushort4*)(xb + (size_t)e1 * Hh + c4);
        ushort4 v2 = *(const ushort4*)(xb + (size_t)e2 * Hh + c4);
        ushort4 v3 = *(const ushort4*)(xb + (size_t)e3 * Hh + c4);
        A1[0] += bf2f(v0.x) + bf2f(v1.x) + bf2f(v2.x) + bf2f(v3.x);
        A1[1] += bf2f(v0.y) + bf2f(v1.y) + bf2f(v2.y) + bf2f(v3.y);
        A1[2] += bf2f(v0.z) + bf2f(v1.z) + bf2f(v2.z) + bf2f(v3.z);
        A1[3] += bf2f(v0.w) + bf2f(v1.w) + bf2f(v2.w) + bf2f(v3.w);
    }
    for (; i + 2 <= e; i += 2) {
        int e0 = csr[i + h];
        ushort4 v = *(const ushort4*)(xb + (size_t)e0 * Hh + c4);
        A1[0] += bf2f(v.x); A1[1] += bf2f(v.y); A1[2] += bf2f(v.z); A1[3] += bf2f(v.w);
    }
    if (i < e && h == 0) {
        ushort4 v = *(const ushort4*)(xb + (size_t)csr[i] * Hh + c4);
        A1[0] += bf2f(v.x); A1[1] += bf2f(v.y); A1[2] += bf2f(v.z); A1[3] += bf2f(v.w);
    }

    // combine the two half-wave partial sums
    #pragma unroll
    for (int j = 0; j < 4; ++j) {
        A0[j] += __shfl_xor(A0[j], 32);
        A1[j] += __shfl_xor(A1[j], 32);
    }

    if (h == 0) {
        float i0 = 1.f / fmaxf((float)(md - s), 1.f);
        float i1 = 1.f / fmaxf((float)(e - md), 1.f);
        uint2 p0, p1;
        p0.x = pk2(A0[0] * i0, A0[1] * i0);
        p0.y = pk2(A0[2] * i0, A0[3] * i0);
        p1.x = pk2(A1[0] * i1, A1[1] * i1);
        p1.y = pk2(A1[2] * i1, A1[3] * i1);
        *(uint2*)(xg0 + (size_t)d * (Hh / 2) + (lane & 31) * 2) = p0;
        *(uint2*)(xg1 + (size_t)d * (Hh / 2) + (lane & 31) * 2) = p1;
    }
}

// ---- fused GEMM: out = relu(xb@root + xg0@W0 + xg1@W1 + b), bf16 out ----
__global__ __launch_bounds__(256) void gemm_fused(const unsigned short* __restrict__ x0,
                                                  const unsigned short* __restrict__ xg0,
                                                  const unsigned short* __restrict__ xg1,
                                                  const unsigned short* __restrict__ wl,
                                                  const float* __restrict__ bias,
                                                  unsigned short* __restrict__ out) {
    int w = threadIdx.x >> 6, lane = threadIdx.x & 63;
    int m = lane & 15, ksel = lane >> 4;
    int row0 = blockIdx.x * 128 + w * 32;

    const unsigned short* srcs[3] = {x0, xg0, xg1};
    bf16x8 a[2][3][4];
    #pragma unroll
    for (int rt = 0; rt < 2; ++rt) {
        int node = row0 + rt * 16 + m;
        #pragma unroll
        for (int mat = 0; mat < 3; ++mat) {
            const unsigned short* xrow = srcs[mat] + (size_t)node * Ff;
            #pragma unroll
            for (int s = 0; s < 4; ++s) {
                if (node < Nn) {
                    a[rt][mat][s] = *(const bf16x8*)(xrow + s * 32 + ksel * 8);
                } else {
                    #pragma unroll
                    for (int q = 0; q < 8; ++q) a[rt][mat][s][q] = 0;
                }
            }
        }
    }

    bool ev = (lane & 1) == 0;
    int j0 = ev ? 0 : 2;

    for (int cb = 0; cb < 8; ++cb) {
        f32x4 acc0 = {0.f, 0.f, 0.f, 0.f};
        f32x4 acc1 = {0.f, 0.f, 0.f, 0.f};
        #pragma unroll
        for (int mat = 0; mat < 3; ++mat) {
            #pragma unroll
            for (int s = 0; s < 4; ++s) {
                bf16x8 bfr = *(const bf16x8*)(wl + ((size_t)((mat * 8 + cb) * 4 + s)) * 512 + lane * 8);
                acc0 = __builtin_amdgcn_mfma_f32_16x16x32_bf16(a[0][mat][s], bfr, acc0, 0, 0, 0);
                acc1 = __builtin_amdgcn_mfma_f32_16x16x32_bf16(a[1][mat][s], bfr, acc1, 0, 0, 0);
            }
        }
        int col = cb * 16 + m;
        float bv = bias[col];
        int colb = col & ~1;
        #pragma unroll
        for (int rt = 0; rt < 2; ++rt) {
            f32x4 ac = rt ? acc1 : acc0;
            float o[4], po[4];
            #pragma unroll
            for (int j = 0; j < 4; ++j) o[j] = fmaxf(ac[j] + bv, 0.f);
            #pragma unroll
            for (int j = 0; j < 4; ++j) po[j] = __shfl_xor(o[j], 1);
            unsigned w0 = ev ? pk2(o[j0], 0.f)     : pk2(po[j0], 0.f);
            // build full words: lo = even col value, hi = odd col value
            unsigned pkw0 = ev ? ((unsigned)f2bf(o[j0])     | ((unsigned)f2bf(po[j0])     << 16))
                               : ((unsigned)f2bf(po[j0])    | ((unsigned)f2bf(o[j0])      << 16));
            unsigned pkw1 = ev ? ((unsigned)f2bf(o[j0 + 1]) | ((unsigned)f2bf(po[j0 + 1]) << 16))
                               : ((unsigned)f2bf(po[j0 + 1])| ((unsigned)f2bf(o[j0 + 1])  << 16));
            (void)w0;
            int rbase = row0 + rt * 16 + ksel * 4;
            int rr0 = rbase + j0, rr1 = rbase + j0 + 1;
            if (rr0 < Nn) *(unsigned*)(out + (size_t)rr0 * Hh + colb) = pkw0;
            if (rr1 < Nn) *(unsigned*)(out + (size_t)rr1 * Hh + colb) = pkw1;
        }
    }
}

// ---- pool + linear: one wave per graph ----
__global__ __launch_bounds__(256) void pool_linear(const unsigned int* __restrict__ xb,
                                                   const int* __restrict__ gstart,
                                                   const float* __restrict__ lin_w,
                                                   const float* __restrict__ lin_b,
                                                   float* __restrict__ out) {
    int g = blockIdx.x * 4 + (threadIdx.x >> 6);
    if (g >= Gg) return;
    int lane = threadIdx.x & 63;
    int s = gstart[g], e = gstart[g + 1];
    float a0 = 0.f, a1 = 0.f;
    for (int n = s; n < e; ++n) {
        unsigned u = xb[(size_t)n * (Hh / 2) + lane];
        a0 += __uint_as_float(u << 16);
        a1 += __uint_as_float(u & 0xffff0000u);
    }
    float inv = 1.f / fmaxf((float)(e - s), 1.f);
    a0 *= inv; a1 *= inv;
    float p[Cc];
    int k0 = 2 * lane, k1 = 2 * lane + 1;
    for (int c = 0; c < Cc; ++c)
        p[c] = a0 * lin_w[k0 * Cc + c] + a1 * lin_w[k1 * Cc + c];
    for (int off = 32; off > 0; off >>= 1)
        for (int c = 0; c < Cc; ++c)
            p[c] += __shfl_down(p[c], off, 64);
    if (lane == 0)
        for (int c = 0; c < Cc; ++c) out[g * Cc + c] = p[c] + lin_b[c];
}

static inline size_t alignup(size_t v) { return (v + 255) & ~(size_t)255; }

extern "C" void kernel_launch(void* const* d_in, const int* in_sizes, int n_in,
                              void* d_out, int out_size, void* d_ws, size_t ws_size,
                              hipStream_t stream) {
    const float* x     = (const float*)d_in[0];
    const int*   ei    = (const int*)d_in[1];
    const int*   ea    = (const int*)d_in[2];
    const int*   batch = (const int*)d_in[3];
    const float* W1 = (const float*)d_in[4];
    const float* r1 = (const float*)d_in[5];
    const float* b1 = (const float*)d_in[6];
    const float* W2 = (const float*)d_in[7];
    const float* r2 = (const float*)d_in[8];
    const float* b2 = (const float*)d_in[9];
    const float* W3 = (const float*)d_in[10];
    const float* r3 = (const float*)d_in[11];
    const float* b3 = (const float*)d_in[12];
    const float* lin_w = (const float*)d_in[13];
    const float* lin_b = (const float*)d_in[14];
    float* out = (float*)d_out;

    char* p = (char*)d_ws;
    unsigned short* xbA = (unsigned short*)p;  p += alignup((size_t)Nn * Hh * 2);
    unsigned short* xbB = (unsigned short*)p;  p += alignup((size_t)Nn * Hh * 2);
    unsigned short* xg0 = (unsigned short*)p;  p += alignup((size_t)Nn * Hh * 2);
    unsigned short* xg1 = (unsigned short*)p;  p += alignup((size_t)Nn * Hh * 2);
    unsigned short* wp  = (unsigned short*)p;  p += alignup((size_t)9 * 16384 * 2);
    int* cnt      = (int*)p;                   p += alignup((size_t)2 * Nn * 4);
    int* rowstart = (int*)p;                   p += alignup((size_t)(Nn + 1) * 4);
    int* mid      = (int*)p;                   p += alignup((size_t)Nn * 4);
    int* cursor   = (int*)p;                   p += alignup((size_t)2 * Nn * 4);
    int* csr      = (int*)p;                   p += alignup((size_t)Ee * 4);
    int* bsum     = (int*)p;                   p += alignup(128 * 4);
    int* gstart   = (int*)p;                   p += alignup((size_t)(Gg + 1) * 4);

    hipMemsetAsync(cnt, 0, (size_t)2 * Nn * 4, stream);

    cast_x<<<(Nn * Ff / 2 + 255) / 256, 256, 0, stream>>>(x, (unsigned int*)xbA);
    pack_w<<<(9 * 16384 + 255) / 256, 256, 0, stream>>>(W1, r1, W2, r2, W3, r3, wp);
    count_edges<<<(Ee + 255) / 256, 256, 0, stream>>>(ei, ea, cnt);
    graph_starts<<<(Nn + 1 + 255) / 256, 256, 0, stream>>>(batch, gstart);

    int nb = (Nn + 1023) / 1024;
    scan_part<<<nb, 256, 0, stream>>>(cnt, rowstart, bsum);
    scan_bsum<<<1, 128, 0, stream>>>(bsum, nb);
    scan_add<<<(Nn + 1 + 255) / 256, 256, 0, stream>>>(rowstart, bsum, cnt, mid, cursor);
    fill_csr<<<4096, 256, 0, stream>>>(ei, ea, cursor, csr);

    int gemm_grid = (Nn + 127) / 128;
    int agg_grid = (Nn + 3) / 4;

    // layer 1: xbA -> xbB
    aggregate<<<agg_grid, 256, 0, stream>>>(xbA, csr, rowstart, mid, (unsigned int*)xg0, (unsigned int*)xg1);
    gemm_fused<<<gemm_grid, 256, 0, stream>>>(xbA, xg0, xg1, wp + 0 * 3 * 16384, b1, xbB);
    // layer 2: xbB -> xbA
    aggregate<<<agg_grid, 256, 0, stream>>>(xbB, csr, rowstart, mid, (unsigned int*)xg0, (unsigned int*)xg1);
    gemm_fused<<<gemm_grid, 256, 0, stream>>>(xbB, xg0, xg1, wp + 1 * 3 * 16384, b2, xbA);
    // layer 3: xbA -> xbB
    aggregate<<<agg_grid, 256, 0, stream>>>(xbA, csr, rowstart, mid, (unsigned int*)xg0, (unsigned int*)xg1);
    gemm_fused<<<gemm_grid, 256, 0, stream>>>(xbA, xg0, xg1, wp + 2 * 3 * 16384, b3, xbB);

    pool_linear<<<(Gg + 3) / 4, 256, 0, stream>>>((const unsigned int*)xbB, gstart, lin_w, lin_b, out);
}